// Round 8
// baseline (71.164 us; speedup 1.0000x reference)
//
#include <hip/hip_runtime.h>

// Problem constants (from reference setup_inputs)
constexpr int B_  = 8;
constexpr int T_  = 16;
constexpr int C_  = 256;
constexpr int HW_ = 784;   // 28*28
constexpr int CO_ = 64;    // C/4
constexpr int K_  = 7;     // KSZ
constexpr int U2_ = 32;    // 2*T

typedef float floatx4 __attribute__((ext_vector_type(4)));

__device__ __forceinline__ float rfl(float v) {
    return __int_as_float(__builtin_amdgcn_readfirstlane(__float_as_int(v)));
}

// ---------------------------------------------------------------------------
// Kernel 1: adaptive avg pool over (h,w): pooled[b,c,t] = mean(x[b,t,c,:,:])
// One wave per (b,t,c) slice of 784 contiguous floats. 4 waves per block.
// ---------------------------------------------------------------------------
__global__ __launch_bounds__(256) void pool_kernel(const float* __restrict__ x,
                                                   float* __restrict__ pooled) {
    int bid  = blockIdx.x;          // (b*T + t)*(C/4) + cg
    int cg   = bid & 63;
    int bt   = bid >> 6;            // b*T + t
    int t    = bt & 15;
    int b    = bt >> 4;
    int wave = threadIdx.x >> 6;
    int lane = threadIdx.x & 63;
    int c    = cg * 4 + wave;

    const floatx4* p4 = (const floatx4*)(x + ((size_t)bt * C_ + c) * HW_);
    float s = 0.f;
    for (int j = lane; j < 196; j += 64) {   // 196 float4 = 784 floats
        floatx4 v = p4[j];
        s += (v.x + v.y) + (v.z + v.w);
    }
#pragma unroll
    for (int m = 32; m >= 1; m >>= 1) s += __shfl_xor(s, m, 64);
    if (lane == 0) pooled[((size_t)b * C_ + c) * T_ + t] = s * (1.0f / 784.0f);
}

// ---------------------------------------------------------------------------
// Kernel 2 (dual role, 2560 blocks):
//   blocks [0,512):    ty[b,o,t] = tanh(conv1d(pooled; Wl1))    (b,o per block)
//   blocks [512,2560): kw[bc][0..6] = softmax(W2 . tanh(W1 . pooled[bc,:]))
// ---------------------------------------------------------------------------
__global__ __launch_bounds__(256) void ty_kw_kernel(const float* __restrict__ pooled,
                                                    const float* __restrict__ Wl1,
                                                    const float* __restrict__ W1,
                                                    const float* __restrict__ W2,
                                                    float* __restrict__ ty,
                                                    float* __restrict__ P) {
    int tid = threadIdx.x;
    if (blockIdx.x < 512) {
        int b = blockIdx.x / CO_;
        int o = blockIdx.x % CO_;
        __shared__ float pld[T_ * 257];   // pld[t*257 + i], padded pitch

        for (int idx = tid; idx < C_ * T_; idx += 256) {
            int i  = idx >> 4;
            int tt = idx & 15;
            pld[tt * 257 + i] = pooled[((size_t)b * C_ + i) * T_ + tt];
        }
        __syncthreads();

        int t = tid >> 4;   // 0..15
        int q = tid & 15;   // i-split
        const float* wrow = Wl1 + (size_t)o * (C_ * K_);
        float acc = 0.f;
        for (int j = 0; j < 16; ++j) {
            int i = j * 16 + q;
            const float* wp = wrow + i * K_;
#pragma unroll
            for (int k = 0; k < K_; ++k) {
                int tt = t + k - 3;
                if (tt >= 0 && tt < T_) acc += wp[k] * pld[tt * 257 + i];
            }
        }
        acc += __shfl_xor(acc, 1, 64);
        acc += __shfl_xor(acc, 2, 64);
        acc += __shfl_xor(acc, 4, 64);
        acc += __shfl_xor(acc, 8, 64);
        if (q == 0) ty[((size_t)b * CO_ + o) * T_ + t] = tanhf(acc);
    } else {
        int bc = blockIdx.x - 512;
        __shared__ float g_s[U2_];
        __shared__ float s_s[8];
        if (tid < U2_) {
            float acc = 0.f;
#pragma unroll
            for (int t2 = 0; t2 < T_; ++t2)
                acc += pooled[(size_t)bc * T_ + t2] * W1[tid * T_ + t2];
            g_s[tid] = tanhf(acc);
        }
        __syncthreads();
        if (tid < K_) {
            float acc = 0.f;
#pragma unroll
            for (int u = 0; u < U2_; ++u) acc += g_s[u] * W2[tid * U2_ + u];
            s_s[tid] = acc;
        }
        __syncthreads();
        if (tid == 0) {
            float m = s_s[0];
#pragma unroll
            for (int k = 1; k < K_; ++k) m = fmaxf(m, s_s[k]);
            float e[K_], sum = 0.f;
#pragma unroll
            for (int k = 0; k < K_; ++k) { e[k] = __expf(s_s[k] - m); sum += e[k]; }
            float inv = 1.0f / sum;
            float* prow = P + (size_t)bc * 8;
#pragma unroll
            for (int k = 0; k < K_; ++k) prow[k] = e[k] * inv;
            prow[7] = 0.f;
        }
    }
}

// ---------------------------------------------------------------------------
// Kernel 3: stream, t-split. One block per (b,c), 448 threads:
//   tid -> (half = tid/196 in {0,1}, col = tid%196); half 2 (tid>=392) idle.
//   half 0 computes out t=0..7 from x t'=0..10; half 1 t=8..15 from t'=5..15.
//   Per-block loc (1 barrier); kw precomputed in P. x loads issued pre-barrier.
// ---------------------------------------------------------------------------
__global__ __launch_bounds__(448) void stream_kernel(const float* __restrict__ x,
                                                     const float* __restrict__ P,
                                                     const float* __restrict__ ty,
                                                     const float* __restrict__ Wl2,
                                                     float* __restrict__ out) {
    int bc = blockIdx.x;         // block-uniform
    int b  = bc >> 8;
    int c  = bc & 255;
    int tid = threadIdx.x;
    int half = tid / 196;        // 0,1 stream; 2 idle
    int col  = tid - half * 196;
    bool active = half < 2;
    int w0 = half * 5;           // window start t'

    const size_t ts = (size_t)C_ * HW_;   // t-stride in floats
    const size_t chan = ((size_t)(b * T_) * C_ + c) * HW_ + (size_t)col * 4;
    const float* xb = x + chan;
    float*       ob = out + chan;

    // ---- Phase A: issue 11 raw x loads (independent of coefficients)
    floatx4 w[11];
    if (active) {
#pragma unroll
        for (int j = 0; j < 11; ++j)
            w[j] = *(const floatx4*)(xb + (size_t)(w0 + j) * ts);
    }

    // ---- Phase B: loc[t] = sigmoid(Wl2[c,:] . ty[b,:,t])  (tid<256, 1 barrier)
    __shared__ float loc_s[T_];
    if (tid < 256) {
        int t = tid >> 4, q = tid & 15;
        float acc = 0.f;
#pragma unroll
        for (int jj = 0; jj < 4; ++jj) {
            int o = q + jj * 16;
            acc += Wl2[(size_t)c * CO_ + o] * ty[((size_t)b * CO_ + o) * T_ + t];
        }
        acc += __shfl_xor(acc, 1, 64);
        acc += __shfl_xor(acc, 2, 64);
        acc += __shfl_xor(acc, 4, 64);
        acc += __shfl_xor(acc, 8, 64);
        if (q == 0) loc_s[t] = 1.0f / (1.0f + __expf(-acc));
    }
    __syncthreads();

    // uniform coefficients -> SGPR
    const float* prow = P + (size_t)bc * 8;
    float kw[K_], lc[T_];
#pragma unroll
    for (int k = 0; k < K_; ++k) kw[k] = rfl(prow[k]);
#pragma unroll
    for (int t = 0; t < T_; ++t) lc[t] = rfl(loc_s[t]);

    if (!active) return;

    // ---- Phase C: gate, 7-tap conv, nt-store
#pragma unroll
    for (int j = 0; j < 11; ++j) w[j] *= lc[w0 + j];

    if (half == 0) {
#pragma unroll
        for (int t = 0; t < 8; ++t) {
            floatx4 acc = {0.f, 0.f, 0.f, 0.f};
#pragma unroll
            for (int d = -3; d <= 3; ++d) {
                int tp = t + d;
                if (tp >= 0 && tp <= 10) acc += kw[d + 3] * w[tp];
            }
            __builtin_nontemporal_store(acc, (floatx4*)(ob + (size_t)t * ts));
        }
    } else {
#pragma unroll
        for (int i = 0; i < 8; ++i) {
            int t = 8 + i;
            floatx4 acc = {0.f, 0.f, 0.f, 0.f};
#pragma unroll
            for (int d = -3; d <= 3; ++d) {
                int tp = t + d;               // 5..18
                if (tp <= 15) acc += kw[d + 3] * w[tp - 5];
            }
            __builtin_nontemporal_store(acc, (floatx4*)(ob + (size_t)t * ts));
        }
    }
}

extern "C" void kernel_launch(void* const* d_in, const int* in_sizes, int n_in,
                              void* d_out, int out_size, void* d_ws, size_t ws_size,
                              hipStream_t stream) {
    const float* x   = (const float*)d_in[0];
    const float* W1  = (const float*)d_in[1];
    const float* W2  = (const float*)d_in[2];
    const float* Wl1 = (const float*)d_in[3];
    const float* Wl2 = (const float*)d_in[4];
    float* out = (float*)d_out;

    float* pooled = (float*)d_ws;              // B*C*T    = 32768 floats
    float* ty     = pooled + B_ * C_ * T_;     // B*CO*T   =  8192 floats
    float* P      = ty + B_ * CO_ * T_;        // B*C*8    = 16384 floats

    pool_kernel<<<B_ * T_ * (C_ / 4), 256, 0, stream>>>(x, pooled);
    ty_kw_kernel<<<512 + B_ * C_, 256, 0, stream>>>(pooled, Wl1, W1, W2, ty, P);
    stream_kernel<<<B_ * C_, 448, 0, stream>>>(x, P, ty, Wl2, out);
}